// Round 1
// baseline (155.597 us; speedup 1.0000x reference)
//
#include <hip/hip_runtime.h>

// multi_triples_lstm on MI355X: per-WG batch-tile LSTM, fp16 MFMA 16x16x32,
// fp32 c-state in registers, h double-buffered fp16 in LDS, 1 barrier/step.
//
// LDS layout (bytes), dynamic:
//   X_all @ 0     : 32 rows x 1040B  (per (b,t): 16 fp16 feats @ b*1040 + t*32)
//   H0    @ 33280 : 32 rows x 80B    (32 fp16 h + pad, 16B-aligned rows)
//   H1    @ 35840 : same
//   ZERO  @ 38400 : 16B of zeros (A-frag k-pad reads, broadcast)
#define LDS_BYTES 38416

typedef _Float16 f16x8 __attribute__((ext_vector_type(8)));
typedef float    f32x4 __attribute__((ext_vector_type(4)));

__device__ __forceinline__ float fast_sigmoid(float x) {
    float e = __builtin_amdgcn_exp2f(x * -1.44269504088896f);   // exp(-x)
    return __builtin_amdgcn_rcpf(1.0f + e);
}
__device__ __forceinline__ float fast_tanh(float x) {
    float e = __builtin_amdgcn_exp2f(x * 2.88539008177793f);    // exp(2x)
    return 1.0f - 2.0f * __builtin_amdgcn_rcpf(1.0f + e);
}

__global__ __launch_bounds__(256, 4)
void lstm_fused(const int* __restrict__ objs,
                const float* __restrict__ boxes,
                const int* __restrict__ preds,
                const int* __restrict__ subj,
                const float* __restrict__ obj_emb,
                const float* __restrict__ pred_emb,
                const float* __restrict__ W_ih,
                const float* __restrict__ W_hh,
                const float* __restrict__ b_ih,
                const float* __restrict__ b_hh,
                const float* __restrict__ fc2_W,
                const float* __restrict__ fc2_b,
                float* __restrict__ out)
{
    extern __shared__ char smem[];
    const int tid   = threadIdx.x;
    const int lane  = tid & 63;
    const int wv    = tid >> 6;          // wave 0..3
    const int quad  = lane >> 4;         // 0..3
    const int cidx  = lane & 15;
    const int jhalf = wv & 1;            // which 16-col half of each gate
    const int Mt    = wv >> 1;           // which 16-row M tile

    const int XOFF = 0, HOFF = 33280, ZOFF = 38400;

    // ---- zero H0+H1+ZERO (5136 B = 1284 dwords); h0 = 0 ----
    {
        int* z = (int*)(smem + HOFF);
        for (int i = tid; i < 1284; i += 256) z[i] = 0;
    }

    // ---- stage all x features (fp16) for this WG's 32 batches x 32 t ----
    {
        int b  = tid >> 3;
        int t0 = (tid & 7) << 2;                     // 4 consecutive t per thread
        long gb = (long)blockIdx.x * 32 + b;
        int4 ov = *(const int4*)(objs  + gb * 32 + t0);
        int4 pv = *(const int4*)(preds + gb * 32 + t0);
        int4 sv = *(const int4*)(subj  + gb * 32 + t0);
        int oarr[4] = {ov.x, ov.y, ov.z, ov.w};
        int parr[4] = {pv.x, pv.y, pv.z, pv.w};
        int sarr[4] = {sv.x, sv.y, sv.z, sv.w};
        #pragma unroll
        for (int tt = 0; tt < 4; ++tt) {
            int t = t0 + tt;
            const float* eo = obj_emb  + oarr[tt] * 5;
            const float* ep = pred_emb + parr[tt] * 5;
            float4 bx = *(const float4*)(boxes + (gb * 32 + t) * 4);
            f16x8 lo, hi;
            lo[0]=(_Float16)eo[0]; lo[1]=(_Float16)eo[1]; lo[2]=(_Float16)eo[2];
            lo[3]=(_Float16)eo[3]; lo[4]=(_Float16)eo[4];
            lo[5]=(_Float16)ep[0]; lo[6]=(_Float16)ep[1]; lo[7]=(_Float16)ep[2];
            hi[0]=(_Float16)ep[3]; hi[1]=(_Float16)ep[4];
            hi[2]=(_Float16)(sarr[tt]==0 ? 1.0f : 0.0f);
            hi[3]=(_Float16)(sarr[tt]==1 ? 1.0f : 0.0f);
            hi[4]=(_Float16)bx.x; hi[5]=(_Float16)bx.y;
            hi[6]=(_Float16)bx.z; hi[7]=(_Float16)bx.w;
            char* dst = smem + XOFF + b * 1040 + t * 32;
            *(f16x8*)dst        = lo;
            *(f16x8*)(dst + 16) = hi;
        }
    }

    // ---- W fragments (fp16, resident in VGPRs) + fused bias ----
    // wave wv owns N-tiles {jhalf, jhalf+2, jhalf+4, jhalf+6} -> i,f,g,o paired in-lane
    f16x8 Wf[4][2];
    float biasv[4];
    #pragma unroll
    for (int g = 0; g < 4; ++g) {
        int n = (jhalf + 2 * g) * 16 + cidx;         // gate row 0..127
        biasv[g] = b_ih[n] + b_hh[n];
        #pragma unroll
        for (int ks = 0; ks < 2; ++ks) {
            f16x8 v;
            #pragma unroll
            for (int jj = 0; jj < 8; ++jj) {
                int k = ks * 32 + quad * 8 + jj;     // A/B k-index
                float val = (k < 16) ? W_ih[n * 16 + k]
                          : (k < 48) ? W_hh[n * 32 + (k - 16)]
                          : 0.0f;
                v[jj] = (_Float16)val;
            }
            Wf[g][ks] = v;
        }
    }

    // ---- A-operand per-lane addresses (k = [x16 | h32 | pad16]) ----
    const int  m_a  = Mt * 16 + cidx;                // A-frag batch row
    const bool isx0 = (quad < 2);
    const int  a0x  = XOFF + m_a * 1040 + quad * 16;           // kstep0, k<16 (x, +32B/t)
    const int  a0h  = HOFF + m_a * 80 + (quad - 2) * 16;       // kstep0, h[0..15]
    const int  a1h  = HOFF + m_a * 80 + 32 + quad * 16;        // kstep1, h[16..31]
    const int  b_row0 = Mt * 16 + quad * 4;                    // C/D batch row base
    const int  kh     = jhalf * 16 + cidx;                     // hidden index
    const int  wrb_base = HOFF + b_row0 * 80 + kh * 2;

    float cst[4] = {0.f, 0.f, 0.f, 0.f};
    float hl[4]  = {0.f, 0.f, 0.f, 0.f};

    __syncthreads();

    for (int t = 0; t < 32; ++t) {
        int sel  = (t & 1) * 2560;                   // read buffer
        int off0 = isx0 ? (a0x + t * 32) : (a0h + sel);
        int off1 = isx0 ? (a1h + sel)    : ZOFF;
        f16x8 a0 = *(const f16x8*)(smem + off0);
        f16x8 a1 = *(const f16x8*)(smem + off1);

        f32x4 acc[4];
        #pragma unroll
        for (int g = 0; g < 4; ++g) {
            float bv = biasv[g];
            f32x4 a = {bv, bv, bv, bv};
            a = __builtin_amdgcn_mfma_f32_16x16x32_f16(a0, Wf[g][0], a, 0, 0, 0);
            a = __builtin_amdgcn_mfma_f32_16x16x32_f16(a1, Wf[g][1], a, 0, 0, 0);
            acc[g] = a;
        }

        int wrb = wrb_base + ((t + 1) & 1) * 2560;   // write the other buffer
        #pragma unroll
        for (int r = 0; r < 4; ++r) {
            float iv = acc[0][r], fv = acc[1][r], gv = acc[2][r], ovl = acc[3][r];
            float si = fast_sigmoid(iv);
            float sf = fast_sigmoid(fv);
            float tg = fast_tanh(gv);
            float so = fast_sigmoid(ovl);
            float cn = sf * cst[r] + si * tg;
            cst[r] = cn;
            float hv = so * fast_tanh(cn);
            hl[r] = hv;
            *(_Float16*)(smem + wrb + 80 * r) = (_Float16)hv;
        }
        __syncthreads();   // writes(t+1) visible before reads at t+1
    }

    // ---- epilogue: fc2 on final h (exact fp32 from registers) ----
    #pragma unroll
    for (int r = 0; r < 4; ++r)
        *(float*)(smem + (b_row0 + r) * 132 + kh * 4) = hl[r];   // 33-float stride
    __syncthreads();

    if (tid < 128) {
        int b = tid >> 2, jj = tid & 3;
        const float* fw   = fc2_W + jj * 32;
        const float* hrow = (const float*)smem + b * 33;
        float s = fc2_b[jj];
        #pragma unroll
        for (int k = 0; k < 32; ++k) s += fw[k] * hrow[k];
        s = fminf(fmaxf(s, 0.0f), 1.0f);
        out[((long)blockIdx.x * 32 + b) * 4 + jj] = s;
    }
}

extern "C" void kernel_launch(void* const* d_in, const int* in_sizes, int n_in,
                              void* d_out, int out_size, void* d_ws, size_t ws_size,
                              hipStream_t stream)
{
    // inputs: 0 objs(i32) 1 boxes(f32) 2 preds(i32) 3 subj(i32) 4 target(unused)
    //         5 obj_emb 6 pred_emb 7 W_ih 8 W_hh 9 b_ih 10 b_hh 11 fc2_W 12 fc2_b
    lstm_fused<<<1024, 256, LDS_BYTES, stream>>>(
        (const int*)d_in[0], (const float*)d_in[1], (const int*)d_in[2],
        (const int*)d_in[3],
        (const float*)d_in[5], (const float*)d_in[6],
        (const float*)d_in[7], (const float*)d_in[8],
        (const float*)d_in[9], (const float*)d_in[10],
        (const float*)d_in[11], (const float*)d_in[12],
        (float*)d_out);
}

// Round 2
// 154.801 us; speedup vs baseline: 1.0051x; 1.0051x over previous
//
#include <hip/hip_runtime.h>

// multi_triples_lstm v2: one wave per 16-batch chain — NO barriers in the
// t-loop. Wave computes full [16x128] gate GEMM (8 N-tiles x 2 ksteps of
// mfma_f32_16x16x32_f16), h single-buffered in LDS (in-wave lgkmcnt order
// only). Activation scales folded into fp16 weights: i/f/o rows * -log2e,
// g rows * +2log2e -> sigmoid = rcp(1+exp2(acc)), tanh = 1-2*rcp(1+exp2(acc)).
//
// LDS (dynamic):
//   X @ 0     : 16 rows x 1040B  (fp16 feats; (b,t) at b*1040 + t*32)
//   H @ 16640 : 16 rows x 80B    (32 fp16 h, 16B-aligned rows, single buffer)
//   Z @ 17920 : 16B zeros        (A-frag k-pad)
//   fc2 scratch reuses X region  (16 rows x 36 f32)
#define LDS_BYTES 17952

typedef _Float16 f16x8 __attribute__((ext_vector_type(8)));
typedef float    f32x4 __attribute__((ext_vector_type(4)));

#define LOG2E     1.44269504088896f
#define TWO_LOG2E 2.88539008177793f

__device__ __forceinline__ float sig_pre(float a) {   // a = -x*log2e
    return __builtin_amdgcn_rcpf(1.0f + __builtin_amdgcn_exp2f(a));
}
__device__ __forceinline__ float tanh_pre(float a) {  // a = 2x*log2e
    return 1.0f - 2.0f * __builtin_amdgcn_rcpf(1.0f + __builtin_amdgcn_exp2f(a));
}

__global__ __launch_bounds__(64, 2)
void lstm_fused(const int* __restrict__ objs,
                const float* __restrict__ boxes,
                const int* __restrict__ preds,
                const int* __restrict__ subj,
                const float* __restrict__ obj_emb,
                const float* __restrict__ pred_emb,
                const float* __restrict__ W_ih,
                const float* __restrict__ W_hh,
                const float* __restrict__ b_ih,
                const float* __restrict__ b_hh,
                const float* __restrict__ fc2_W,
                const float* __restrict__ fc2_b,
                float* __restrict__ out)
{
    extern __shared__ char smem[];
    const int tid  = threadIdx.x;        // == lane, block is one wave
    const int quad = tid >> 4;           // 0..3
    const int cidx = tid & 15;
    const int XOFF = 0, HOFF = 16640, ZOFF = 17920;

    // ---- zero H + zero-pad region (1312 B = 328 dwords); h0 = c0 = 0 ----
    {
        int* z = (int*)(smem + HOFF);
        #pragma unroll
        for (int i = 0; i < 6; ++i) {
            int idx = tid + i * 64;
            if (idx < 328) z[idx] = 0;
        }
    }

    // ---- stage x features (fp16) for 16 batches x 32 t ----
    {
        int b  = tid >> 2;               // 0..15
        int t0 = (tid & 3) << 3;         // 0,8,16,24 — 8 t per thread
        long gb = (long)blockIdx.x * 16 + b;
        const int* op = objs  + gb * 32 + t0;
        const int* pp = preds + gb * 32 + t0;
        const int* sp = subj  + gb * 32 + t0;
        #pragma unroll
        for (int c = 0; c < 8; c += 4) {
            int4 ov = *(const int4*)(op + c);
            int4 pv = *(const int4*)(pp + c);
            int4 sv = *(const int4*)(sp + c);
            int oarr[4] = {ov.x, ov.y, ov.z, ov.w};
            int parr[4] = {pv.x, pv.y, pv.z, pv.w};
            int sarr[4] = {sv.x, sv.y, sv.z, sv.w};
            #pragma unroll
            for (int tt = 0; tt < 4; ++tt) {
                int t = t0 + c + tt;
                const float* eo = obj_emb  + oarr[tt] * 5;
                const float* ep = pred_emb + parr[tt] * 5;
                float4 bx = *(const float4*)(boxes + (gb * 32 + t) * 4);
                f16x8 lo, hi;
                lo[0]=(_Float16)eo[0]; lo[1]=(_Float16)eo[1]; lo[2]=(_Float16)eo[2];
                lo[3]=(_Float16)eo[3]; lo[4]=(_Float16)eo[4];
                lo[5]=(_Float16)ep[0]; lo[6]=(_Float16)ep[1]; lo[7]=(_Float16)ep[2];
                hi[0]=(_Float16)ep[3]; hi[1]=(_Float16)ep[4];
                hi[2]=(_Float16)(sarr[tt]==0 ? 1.0f : 0.0f);
                hi[3]=(_Float16)(sarr[tt]==1 ? 1.0f : 0.0f);
                hi[4]=(_Float16)bx.x; hi[5]=(_Float16)bx.y;
                hi[6]=(_Float16)bx.z; hi[7]=(_Float16)bx.w;
                char* dst = smem + XOFF + b * 1040 + t * 32;
                *(f16x8*)dst        = lo;
                *(f16x8*)(dst + 16) = hi;
            }
        }
    }

    // ---- W fragments (fp16, pre-scaled) + scaled bias as MFMA C ----
    // tile j covers gates [16j,16j+16): j 0,1 = i; 2,3 = f; 4,5 = g; 6,7 = o
    f16x8 Wf[8][2];
    f32x4 bias4[8];
    #pragma unroll
    for (int j = 0; j < 8; ++j) {
        int n = j * 16 + cidx;                       // gate row 0..127
        float scale = (j >= 4 && j < 6) ? TWO_LOG2E : -LOG2E;
        float bv = (b_ih[n] + b_hh[n]) * scale;
        bias4[j] = (f32x4){bv, bv, bv, bv};
        #pragma unroll
        for (int ks = 0; ks < 2; ++ks) {
            f16x8 v;
            #pragma unroll
            for (int jj = 0; jj < 8; ++jj) {
                int k = ks * 32 + quad * 8 + jj;     // k = [x16 | h32 | pad16]
                float val = (k < 16) ? W_ih[n * 16 + k]
                          : (k < 48) ? W_hh[n * 32 + (k - 16)]
                          : 0.0f;
                v[jj] = (_Float16)(val * scale);
            }
            Wf[j][ks] = v;
        }
    }

    // ---- A-operand per-lane addresses ----
    const bool isx  = (quad < 2);
    int addr0 = isx ? (XOFF + cidx * 1040 + quad * 16)           // x[0:16]
                    : (HOFF + cidx * 80 + (quad - 2) * 16);      // h[0:16]
    const int inc0  = isx ? 32 : 0;                              // x advances per t
    const int addr1 = isx ? (HOFF + cidx * 80 + 32 + quad * 16)  // h[16:32]
                          : ZOFF;                                // k-pad zeros
    const int wr_b  = quad * 4;                                  // C/D batch row base

    float cst[8] = {0,0,0,0,0,0,0,0};
    float hl[8];

    __syncthreads();   // single wave: cheap; orders staging vs t-loop

    #pragma unroll 4
    for (int t = 0; t < 32; ++t) {
        f16x8 a0 = *(const f16x8*)(smem + addr0);
        f16x8 a1 = *(const f16x8*)(smem + addr1);
        addr0 += inc0;

        f32x4 acc[8];
        #pragma unroll
        for (int j = 0; j < 8; ++j) {
            f32x4 a = __builtin_amdgcn_mfma_f32_16x16x32_f16(a0, Wf[j][0], bias4[j], 0, 0, 0);
            acc[j]  = __builtin_amdgcn_mfma_f32_16x16x32_f16(a1, Wf[j][1], a, 0, 0, 0);
        }

        #pragma unroll
        for (int r = 0; r < 4; ++r) {
            float si0 = sig_pre(acc[0][r]);
            float si1 = sig_pre(acc[1][r]);
            float sf0 = sig_pre(acc[2][r]);
            float sf1 = sig_pre(acc[3][r]);
            float tg0 = tanh_pre(acc[4][r]);
            float tg1 = tanh_pre(acc[5][r]);
            float so0 = sig_pre(acc[6][r]);
            float so1 = sig_pre(acc[7][r]);
            float c0 = fmaf(sf0, cst[2*r],   si0 * tg0);
            float c1 = fmaf(sf1, cst[2*r+1], si1 * tg1);
            cst[2*r] = c0; cst[2*r+1] = c1;
            float h0 = so0 * tanh_pre(c0 * TWO_LOG2E);
            float h1 = so1 * tanh_pre(c1 * TWO_LOG2E);
            hl[2*r] = h0; hl[2*r+1] = h1;
            *(_Float16*)(smem + HOFF + (wr_b + r) * 80 + cidx * 2)      = (_Float16)h0;
            *(_Float16*)(smem + HOFF + (wr_b + r) * 80 + 32 + cidx * 2) = (_Float16)h1;
        }
        // in-order wave: next iteration's ds_read waits on lgkmcnt; no barrier
    }

    // ---- epilogue: fc2 on final h (fp32 from registers via LDS scratch) ----
    __syncthreads();
    #pragma unroll
    for (int r = 0; r < 4; ++r) {
        *(float*)(smem + (wr_b + r) * 144 + cidx * 4)      = hl[2*r];
        *(float*)(smem + (wr_b + r) * 144 + 64 + cidx * 4) = hl[2*r+1];
    }
    __syncthreads();

    {
        int b = tid >> 2, jj = tid & 3;
        const float* fw   = fc2_W + jj * 32;
        const float* hrow = (const float*)(smem + b * 144);
        float s = fc2_b[jj];
        #pragma unroll
        for (int k = 0; k < 8; ++k) {
            float4 hv = *(const float4*)(hrow + k * 4);
            s += fw[k*4+0] * hv.x + fw[k*4+1] * hv.y
               + fw[k*4+2] * hv.z + fw[k*4+3] * hv.w;
        }
        s = fminf(fmaxf(s, 0.0f), 1.0f);
        out[(long)blockIdx.x * 64 + tid] = s;
    }
}

extern "C" void kernel_launch(void* const* d_in, const int* in_sizes, int n_in,
                              void* d_out, int out_size, void* d_ws, size_t ws_size,
                              hipStream_t stream)
{
    // inputs: 0 objs(i32) 1 boxes(f32) 2 preds(i32) 3 subj(i32) 4 target(unused)
    //         5 obj_emb 6 pred_emb 7 W_ih 8 W_hh 9 b_ih 10 b_hh 11 fc2_W 12 fc2_b
    lstm_fused<<<2048, 64, LDS_BYTES, stream>>>(
        (const int*)d_in[0], (const float*)d_in[1], (const int*)d_in[2],
        (const int*)d_in[3],
        (const float*)d_in[5], (const float*)d_in[6],
        (const float*)d_in[7], (const float*)d_in[8],
        (const float*)d_in[9], (const float*)d_in[10],
        (const float*)d_in[11], (const float*)d_in[12],
        (float*)d_out);
}

// Round 3
// 145.974 us; speedup vs baseline: 1.0659x; 1.0605x over previous
//
#include <hip/hip_runtime.h>

// multi_triples_lstm v3: role-swapped MFMA (A=W, B=activations, D[gate][batch])
// so batch lives in lane&15 everywhere -> h recurrence crosses steps via
// ds_bpermute (register exchange), NO LDS write->read round trip.
// K layout [x16 | pad16 | h32]: x-MFMAs of step t+1 are h-independent and
// overlap step t's activation chain. One wave per 16-batch chain, no barriers.
//
// LDS (dynamic):
//   X @ 0     : 16 rows x 1040B (fp16 feats; (b,t) at b*1040 + t*32; 16B pad)
//   Z @ 16640 : 16B zeros (k-pad reads; also absorbs the t=32 dummy prefetch)
//   fc2 scratch overlays X (16 rows x 36 f32)
#define LDS_BYTES 16656

typedef _Float16 f16x8 __attribute__((ext_vector_type(8)));
typedef float    f32x4 __attribute__((ext_vector_type(4)));

#define LOG2E     1.44269504088896f
#define TWO_LOG2E 2.88539008177793f

__device__ __forceinline__ float sig_pre(float a) {   // a = -x*log2e
    return __builtin_amdgcn_rcpf(1.0f + __builtin_amdgcn_exp2f(a));
}
__device__ __forceinline__ float tanh_pre(float a) {  // a = 2x*log2e
    return 1.0f - 2.0f * __builtin_amdgcn_rcpf(1.0f + __builtin_amdgcn_exp2f(a));
}
__device__ __forceinline__ int pack2(float a, float b) {  // RTN fp16 pair
    union { _Float16 h[2]; int i; } u;
    u.h[0] = (_Float16)a; u.h[1] = (_Float16)b;
    return u.i;
}

__global__ __launch_bounds__(64, 2)
void lstm_fused(const int* __restrict__ objs,
                const float* __restrict__ boxes,
                const int* __restrict__ preds,
                const int* __restrict__ subj,
                const float* __restrict__ obj_emb,
                const float* __restrict__ pred_emb,
                const float* __restrict__ W_ih,
                const float* __restrict__ W_hh,
                const float* __restrict__ b_ih,
                const float* __restrict__ b_hh,
                const float* __restrict__ fc2_W,
                const float* __restrict__ fc2_b,
                float* __restrict__ out)
{
    extern __shared__ char smem[];
    const int tid  = threadIdx.x;        // == lane, one wave per block
    const int quad = tid >> 4;           // 0..3
    const int cidx = tid & 15;           // batch index everywhere
    const int XOFF = 0, ZOFF = 16640;

    if (tid < 4) ((int*)(smem + ZOFF))[tid] = 0;

    // ---- stage x features (fp16) for 16 batches x 32 t ----
    {
        int b  = tid >> 2;               // 0..15
        int t0 = (tid & 3) << 3;         // 8 t per thread
        long gb = (long)blockIdx.x * 16 + b;
        const int* op = objs  + gb * 32 + t0;
        const int* pp = preds + gb * 32 + t0;
        const int* sp = subj  + gb * 32 + t0;
        #pragma unroll
        for (int c = 0; c < 8; c += 4) {
            int4 ov = *(const int4*)(op + c);
            int4 pv = *(const int4*)(pp + c);
            int4 sv = *(const int4*)(sp + c);
            int oarr[4] = {ov.x, ov.y, ov.z, ov.w};
            int parr[4] = {pv.x, pv.y, pv.z, pv.w};
            int sarr[4] = {sv.x, sv.y, sv.z, sv.w};
            #pragma unroll
            for (int tt = 0; tt < 4; ++tt) {
                int t = t0 + c + tt;
                const float* eo = obj_emb  + oarr[tt] * 5;
                const float* ep = pred_emb + parr[tt] * 5;
                float4 bx = *(const float4*)(boxes + (gb * 32 + t) * 4);
                f16x8 lo, hi;
                lo[0]=(_Float16)eo[0]; lo[1]=(_Float16)eo[1]; lo[2]=(_Float16)eo[2];
                lo[3]=(_Float16)eo[3]; lo[4]=(_Float16)eo[4];
                lo[5]=(_Float16)ep[0]; lo[6]=(_Float16)ep[1]; lo[7]=(_Float16)ep[2];
                hi[0]=(_Float16)ep[3]; hi[1]=(_Float16)ep[4];
                hi[2]=(_Float16)(sarr[tt]==0 ? 1.0f : 0.0f);
                hi[3]=(_Float16)(sarr[tt]==1 ? 1.0f : 0.0f);
                hi[4]=(_Float16)bx.x; hi[5]=(_Float16)bx.y;
                hi[6]=(_Float16)bx.z; hi[7]=(_Float16)bx.w;
                char* dst = smem + XOFF + b * 1040 + t * 32;
                *(f16x8*)dst        = lo;
                *(f16x8*)(dst + 16) = hi;
            }
        }
    }

    // ---- W as A-operand fragments (fp16, pre-scaled), K = [x16|pad16|h32] ----
    // tile j: gate rows 16j..16j+15. A[m][k]: m = cidx (gate row), k = quad*8+jj
    // scales folded: i/f/o rows * -log2e, g rows * +2log2e
    f16x8 Wf[8][2];
    f32x4 bias4[8];
    #pragma unroll
    for (int j = 0; j < 8; ++j) {
        float scale = (j == 4 || j == 5) ? TWO_LOG2E : -LOG2E;
        int n = j * 16 + cidx;
        #pragma unroll
        for (int ks = 0; ks < 2; ++ks) {
            f16x8 v;
            #pragma unroll
            for (int jj = 0; jj < 8; ++jj) {
                int k = ks * 32 + quad * 8 + jj;
                float val = (k < 16) ? W_ih[n * 16 + k]
                          : (k >= 32) ? W_hh[n * 32 + (k - 32)]
                          : 0.0f;
                v[jj] = (_Float16)(val * scale);
            }
            Wf[j][ks] = v;
        }
        // bias rides as MFMA C: D row = gate = 16j + quad*4 + r
        #pragma unroll
        for (int r = 0; r < 4; ++r) {
            int nr = j * 16 + quad * 4 + r;
            bias4[j][r] = (b_ih[nr] + b_hh[nr]) * scale;
        }
    }

    // ---- B-operand addressing ----
    // kstep0: quads 0,1 = x features, quads 2,3 = zeros (ZOFF)
    const bool qlow = (quad < 2);
    int       xaddr = qlow ? (XOFF + cidx * 1040 + quad * 16) : ZOFF;
    const int xinc  = qlow ? 32 : 0;
    // h exchange: dest lane (q,c) pulls from lanes s_lo=(q&1)*32+c, s_hi=s_lo+16
    const int idx_lo = (((quad & 1) << 5) + cidx) << 2;
    const int idx_hi = idx_lo + 64;

    __syncthreads();   // one wave: just orders staging writes vs reads

    // prime: x[0] and its MFMAs
    f16x8 xfrag = *(const f16x8*)(smem + xaddr); xaddr += xinc;
    f32x4 accp[8];
    #pragma unroll
    for (int j = 0; j < 8; ++j)
        accp[j] = __builtin_amdgcn_mfma_f32_16x16x32_f16(Wf[j][0], xfrag, bias4[j], 0, 0, 0);

    int pkA = 0, pkB = 0, pkC = 0, pkD = 0;   // packed h: (r0,r1|r2,r3) x (tile0|tile1)
    float cst[8] = {0,0,0,0,0,0,0,0};
    float hl[8];

    #pragma unroll 4
    for (int t = 0; t < 32; ++t) {
        // h-frag for this step via cross-lane pull (zero at t=0)
        int pa_lo = __builtin_amdgcn_ds_bpermute(idx_lo, pkA);
        int pb_lo = __builtin_amdgcn_ds_bpermute(idx_lo, pkB);
        int pa_hi = __builtin_amdgcn_ds_bpermute(idx_hi, pkA);
        int pb_hi = __builtin_amdgcn_ds_bpermute(idx_hi, pkB);
        int pc_lo = __builtin_amdgcn_ds_bpermute(idx_lo, pkC);
        int pd_lo = __builtin_amdgcn_ds_bpermute(idx_lo, pkD);
        int pc_hi = __builtin_amdgcn_ds_bpermute(idx_hi, pkC);
        int pd_hi = __builtin_amdgcn_ds_bpermute(idx_hi, pkD);
        union { int i[4]; f16x8 v; } hf;
        hf.i[0] = qlow ? pa_lo : pc_lo;
        hf.i[1] = qlow ? pb_lo : pd_lo;
        hf.i[2] = qlow ? pa_hi : pc_hi;
        hf.i[3] = qlow ? pb_hi : pd_hi;

        f32x4 acc[8];
        #pragma unroll
        for (int j = 0; j < 8; ++j)
            acc[j] = __builtin_amdgcn_mfma_f32_16x16x32_f16(Wf[j][1], hf.v, accp[j], 0, 0, 0);

        // prefetch next x (t=31 reads row pad / ZOFF — discarded)
        f16x8 xn = *(const f16x8*)(smem + xaddr); xaddr += xinc;

        // activations: lane owns batch cidx, gates quad*4+r (+16) of each type
        #pragma unroll
        for (int r = 0; r < 4; ++r) {
            float si0 = sig_pre(acc[0][r]);
            float si1 = sig_pre(acc[1][r]);
            float sf0 = sig_pre(acc[2][r]);
            float sf1 = sig_pre(acc[3][r]);
            float tg0 = tanh_pre(acc[4][r]);
            float tg1 = tanh_pre(acc[5][r]);
            float so0 = sig_pre(acc[6][r]);
            float so1 = sig_pre(acc[7][r]);
            float c0 = fmaf(sf0, cst[2*r],   si0 * tg0);
            float c1 = fmaf(sf1, cst[2*r+1], si1 * tg1);
            cst[2*r] = c0; cst[2*r+1] = c1;
            hl[2*r]   = so0 * tanh_pre(c0 * TWO_LOG2E);
            hl[2*r+1] = so1 * tanh_pre(c1 * TWO_LOG2E);
        }
        // pack h for next step's exchange: tile0=(hu 4q..4q+3), tile1=(+16)
        pkA = pack2(hl[0], hl[2]);
        pkB = pack2(hl[4], hl[6]);
        pkC = pack2(hl[1], hl[3]);
        pkD = pack2(hl[5], hl[7]);

        // x-MFMAs for next step — independent of h chain, fills MFMA pipe
        #pragma unroll
        for (int j = 0; j < 8; ++j)
            accp[j] = __builtin_amdgcn_mfma_f32_16x16x32_f16(Wf[j][0], xn, bias4[j], 0, 0, 0);
    }

    // ---- epilogue: fc2 on final h (fp32 via LDS scratch over X) ----
    __syncthreads();
    #pragma unroll
    for (int r = 0; r < 4; ++r) {
        *(float*)(smem + cidx * 144 + (quad * 4 + r) * 4)        = hl[2*r];
        *(float*)(smem + cidx * 144 + (16 + quad * 4 + r) * 4)   = hl[2*r+1];
    }
    __syncthreads();

    {
        int b = tid >> 2, jj = tid & 3;
        const float* fw   = fc2_W + jj * 32;
        const float* hrow = (const float*)(smem + b * 144);
        float s = fc2_b[jj];
        #pragma unroll
        for (int k = 0; k < 8; ++k) {
            float4 hv = *(const float4*)(hrow + k * 4);
            s += fw[k*4+0] * hv.x + fw[k*4+1] * hv.y
               + fw[k*4+2] * hv.z + fw[k*4+3] * hv.w;
        }
        s = fminf(fmaxf(s, 0.0f), 1.0f);
        out[(long)blockIdx.x * 64 + tid] = s;
    }
}

extern "C" void kernel_launch(void* const* d_in, const int* in_sizes, int n_in,
                              void* d_out, int out_size, void* d_ws, size_t ws_size,
                              hipStream_t stream)
{
    // inputs: 0 objs(i32) 1 boxes(f32) 2 preds(i32) 3 subj(i32) 4 target(unused)
    //         5 obj_emb 6 pred_emb 7 W_ih 8 W_hh 9 b_ih 10 b_hh 11 fc2_W 12 fc2_b
    lstm_fused<<<2048, 64, LDS_BYTES, stream>>>(
        (const int*)d_in[0], (const float*)d_in[1], (const int*)d_in[2],
        (const int*)d_in[3],
        (const float*)d_in[5], (const float*)d_in[6],
        (const float*)d_in[7], (const float*)d_in[8],
        (const float*)d_in[9], (const float*)d_in[10],
        (const float*)d_in[11], (const float*)d_in[12],
        (float*)d_out);
}

// Round 4
// 145.621 us; speedup vs baseline: 1.0685x; 1.0024x over previous
//
#include <hip/hip_runtime.h>

// multi_triples_lstm v4: fully in-register recurrence. Gate rows of W are
// permuted per 16-row tile (m -> 8*(m>>2)+(m&3)+4*half) so each lane's MFMA
// D-outputs are exactly the h-units it supplies as next step's B-operand
// fragment (k=8*quad+jj). h crosses steps via 4 v_pack regs — no LDS, no
// bpermute, no barrier in the t-loop. One wave per 16-batch chain.
// Scales folded into fp16 weights: i/f/o rows * -log2e, g rows * +2log2e.
//
// LDS (dynamic):
//   X @ 0     : 16 rows x 1040B (fp16 feats; (b,t) at b*1040 + t*32)
//   Z @ 16640 : 16B zeros (x-frag quads 2,3) + 16B guard (t=31 prefetch)
//   fc2 scratch overlays X (16 rows x 36 f32)
#define LDS_BYTES 16672

typedef _Float16 f16x8 __attribute__((ext_vector_type(8)));
typedef float    f32x4 __attribute__((ext_vector_type(4)));

#define LOG2E     1.44269504088896f
#define TWO_LOG2E 2.88539008177793f

__device__ __forceinline__ float sig_pre(float a) {   // a = -x*log2e
    return __builtin_amdgcn_rcpf(1.0f + __builtin_amdgcn_exp2f(a));
}
__device__ __forceinline__ float tanh_pre(float a) {  // a = 2x*log2e
    return 1.0f - 2.0f * __builtin_amdgcn_rcpf(1.0f + __builtin_amdgcn_exp2f(a));
}
__device__ __forceinline__ int pack2(float a, float b) {  // RTN fp16 pair
    union { _Float16 h[2]; int i; } u;
    u.h[0] = (_Float16)a; u.h[1] = (_Float16)b;
    return u.i;
}

__global__ __launch_bounds__(64, 2)
void lstm_fused(const int* __restrict__ objs,
                const float* __restrict__ boxes,
                const int* __restrict__ preds,
                const int* __restrict__ subj,
                const float* __restrict__ obj_emb,
                const float* __restrict__ pred_emb,
                const float* __restrict__ W_ih,
                const float* __restrict__ W_hh,
                const float* __restrict__ b_ih,
                const float* __restrict__ b_hh,
                const float* __restrict__ fc2_W,
                const float* __restrict__ fc2_b,
                float* __restrict__ out)
{
    extern __shared__ char smem[];
    const int tid  = threadIdx.x;        // == lane, one wave per block
    const int quad = tid >> 4;           // 0..3
    const int cidx = tid & 15;           // batch index everywhere
    const int XOFF = 0, ZOFF = 16640;

    if (tid < 8) ((int*)(smem + ZOFF))[tid] = 0;

    // ---- stage x features (fp16) for 16 batches x 32 t ----
    {
        int b  = tid >> 2;               // 0..15
        int t0 = (tid & 3) << 3;         // 8 t per thread
        long gb = (long)blockIdx.x * 16 + b;
        const int* op = objs  + gb * 32 + t0;
        const int* pp = preds + gb * 32 + t0;
        const int* sp = subj  + gb * 32 + t0;
        #pragma unroll
        for (int c = 0; c < 8; c += 4) {
            int4 ov = *(const int4*)(op + c);
            int4 pv = *(const int4*)(pp + c);
            int4 sv = *(const int4*)(sp + c);
            int oarr[4] = {ov.x, ov.y, ov.z, ov.w};
            int parr[4] = {pv.x, pv.y, pv.z, pv.w};
            int sarr[4] = {sv.x, sv.y, sv.z, sv.w};
            #pragma unroll
            for (int tt = 0; tt < 4; ++tt) {
                int t = t0 + c + tt;
                const float* eo = obj_emb  + oarr[tt] * 5;
                const float* ep = pred_emb + parr[tt] * 5;
                float4 bx = *(const float4*)(boxes + (gb * 32 + t) * 4);
                f16x8 lo, hi;
                lo[0]=(_Float16)eo[0]; lo[1]=(_Float16)eo[1]; lo[2]=(_Float16)eo[2];
                lo[3]=(_Float16)eo[3]; lo[4]=(_Float16)eo[4];
                lo[5]=(_Float16)ep[0]; lo[6]=(_Float16)ep[1]; lo[7]=(_Float16)ep[2];
                hi[0]=(_Float16)ep[3]; hi[1]=(_Float16)ep[4];
                hi[2]=(_Float16)(sarr[tt]==0 ? 1.0f : 0.0f);
                hi[3]=(_Float16)(sarr[tt]==1 ? 1.0f : 0.0f);
                hi[4]=(_Float16)bx.x; hi[5]=(_Float16)bx.y;
                hi[6]=(_Float16)bx.z; hi[7]=(_Float16)bx.w;
                char* dst = smem + XOFF + b * 1040 + t * 32;
                *(f16x8*)dst        = lo;
                *(f16x8*)(dst + 16) = hi;
            }
        }
    }

    // ---- W as A-operand fragments (fp16, pre-scaled), K = [x16|pad16|h32] ----
    // tile j = 2g+half (g: 0=i,1=f,2=g,3=o). Tile-row m <-> hidden unit
    // u(m) = 8*(m>>2) + (m&3) + 4*half. A-frag: m=cidx, k=quad*8+jj.
    // => lane(q,c)'s D rows (m=4q+r) are units {8q+r+4*half}: exactly the
    //    B-frag slots k=32+8q+jj it feeds next step.
    f16x8 Wf[8][2];
    f32x4 bias4[8];
    #pragma unroll
    for (int j = 0; j < 8; ++j) {
        int g = j >> 1, half = j & 1;
        float scale = (g == 2) ? TWO_LOG2E : -LOG2E;
        int um = 8 * (cidx >> 2) + (cidx & 3) + 4 * half;  // unit for A row
        int n  = g * 32 + um;                              // canonical W row
        #pragma unroll
        for (int ks = 0; ks < 2; ++ks) {
            f16x8 v;
            #pragma unroll
            for (int jj = 0; jj < 8; ++jj) {
                int k = ks * 32 + quad * 8 + jj;
                float val = (k < 16) ? W_ih[n * 16 + k]
                          : (k >= 32) ? W_hh[n * 32 + (k - 32)]
                          : 0.0f;
                v[jj] = (_Float16)(val * scale);
            }
            Wf[j][ks] = v;
        }
        #pragma unroll
        for (int r = 0; r < 4; ++r) {
            int ur = 8 * quad + r + 4 * half;              // unit for D row
            bias4[j][r] = (b_ih[g * 32 + ur] + b_hh[g * 32 + ur]) * scale;
        }
    }

    // ---- x B-frag addressing (kstep0: quads 0,1 = x, quads 2,3 = zeros) ----
    const bool qlow = (quad < 2);
    int       xaddr = qlow ? (XOFF + cidx * 1040 + quad * 16) : ZOFF;
    const int xinc  = qlow ? 32 : 0;

    __syncthreads();   // staging visible (single wave: just a fence)

    // prime: x[0] MFMAs (bias rides as C)
    f16x8 xfrag = *(const f16x8*)(smem + xaddr); xaddr += xinc;
    f32x4 accp[8];
    #pragma unroll
    for (int j = 0; j < 8; ++j)
        accp[j] = __builtin_amdgcn_mfma_f32_16x16x32_f16(Wf[j][0], xfrag, bias4[j], 0, 0, 0);

    int pk0 = 0, pk1 = 0, pk2 = 0, pk3 = 0;   // packed h = next B-frag
    float cst[8] = {0,0,0,0,0,0,0,0};
    float h_lo[4], h_hi[4];

    #pragma unroll 2
    for (int t = 0; t < 32; ++t) {
        union { int i[4]; f16x8 v; } hf;
        hf.i[0] = pk0; hf.i[1] = pk1; hf.i[2] = pk2; hf.i[3] = pk3;

        f32x4 acc[8];
        #pragma unroll
        for (int j = 0; j < 8; ++j)
            acc[j] = __builtin_amdgcn_mfma_f32_16x16x32_f16(Wf[j][1], hf.v, accp[j], 0, 0, 0);

        // prefetch next x (t=31 reads Z/guard — discarded)
        f16x8 xn = *(const f16x8*)(smem + xaddr); xaddr += xinc;

        // activations: lane(q,c) = batch c, units 8q+r (lo) / 8q+4+r (hi)
        #pragma unroll
        for (int r = 0; r < 4; ++r) {
            float i0 = sig_pre(acc[0][r]);
            float i1 = sig_pre(acc[1][r]);
            float f0 = sig_pre(acc[2][r]);
            float f1 = sig_pre(acc[3][r]);
            float g0 = tanh_pre(acc[4][r]);
            float g1 = tanh_pre(acc[5][r]);
            float o0 = sig_pre(acc[6][r]);
            float o1 = sig_pre(acc[7][r]);
            float c0 = fmaf(f0, cst[r],     i0 * g0);
            float c1 = fmaf(f1, cst[4 + r], i1 * g1);
            cst[r] = c0; cst[4 + r] = c1;
            h_lo[r] = o0 * tanh_pre(c0 * TWO_LOG2E);
            h_hi[r] = o1 * tanh_pre(c1 * TWO_LOG2E);
        }
        // pack: B-frag v[jj] = h[8q+jj] -> v[0:4]=lo, v[4:8]=hi
        pk0 = pack2(h_lo[0], h_lo[1]);
        pk1 = pack2(h_lo[2], h_lo[3]);
        pk2 = pack2(h_hi[0], h_hi[1]);
        pk3 = pack2(h_hi[2], h_hi[3]);

        // x-MFMAs for next step — off the h critical path
        #pragma unroll
        for (int j = 0; j < 8; ++j)
            accp[j] = __builtin_amdgcn_mfma_f32_16x16x32_f16(Wf[j][0], xn, bias4[j], 0, 0, 0);
    }

    // ---- epilogue: fc2 on final h (fp32 via LDS scratch over X) ----
    __syncthreads();
    #pragma unroll
    for (int r = 0; r < 4; ++r) {
        *(float*)(smem + cidx * 144 + (8 * quad + r) * 4)     = h_lo[r];
        *(float*)(smem + cidx * 144 + (8 * quad + 4 + r) * 4) = h_hi[r];
    }
    __syncthreads();

    {
        int b = tid >> 2, jj = tid & 3;
        const float* fw   = fc2_W + jj * 32;
        const float* hrow = (const float*)(smem + b * 144);
        float s = fc2_b[jj];
        #pragma unroll
        for (int k = 0; k < 8; ++k) {
            float4 hv = *(const float4*)(hrow + k * 4);
            s += fw[k*4+0] * hv.x + fw[k*4+1] * hv.y
               + fw[k*4+2] * hv.z + fw[k*4+3] * hv.w;
        }
        s = fminf(fmaxf(s, 0.0f), 1.0f);
        out[(long)blockIdx.x * 64 + tid] = s;
    }
}

extern "C" void kernel_launch(void* const* d_in, const int* in_sizes, int n_in,
                              void* d_out, int out_size, void* d_ws, size_t ws_size,
                              hipStream_t stream)
{
    // inputs: 0 objs(i32) 1 boxes(f32) 2 preds(i32) 3 subj(i32) 4 target(unused)
    //         5 obj_emb 6 pred_emb 7 W_ih 8 W_hh 9 b_ih 10 b_hh 11 fc2_W 12 fc2_b
    lstm_fused<<<2048, 64, LDS_BYTES, stream>>>(
        (const int*)d_in[0], (const float*)d_in[1], (const int*)d_in[2],
        (const int*)d_in[3],
        (const float*)d_in[5], (const float*)d_in[6],
        (const float*)d_in[7], (const float*)d_in[8],
        (const float*)d_in[9], (const float*)d_in[10],
        (const float*)d_in[11], (const float*)d_in[12],
        (float*)d_out);
}

// Round 5
// 143.593 us; speedup vs baseline: 1.0836x; 1.0141x over previous
//
#include <hip/hip_runtime.h>

// multi_triples_lstm v5: gate-split 2-wave workgroups -> 4096 waves (4/SIMD).
// WG = one 16-batch chain; wave w computes gate-tiles (i,f,g,o) x half=w:
// 4 x-MFMAs + 4 h-MFMAs + 40 trans per step (half of v4). Lane(q,c) of wave w
// produces h-units {8q+4w+r} (v4's row permutation) = half of its next
// B-fragment; other half exchanged via ds_write_b64/ds_read_b64 + s_barrier
// (double-buffered, one barrier/step). Scales folded into fp16 weights.
//
// LDS (dynamic):
//   X   @ 0     : 16 rows x 1040B (fp16 feats; (b,t) at b*1040 + t*32)
//   HX0 @ 16640 : 1024B (2 waves x 64 lanes x 8B packed h)
//   HX1 @ 17664 : 1024B (double buffer)
//   Z   @ 18688 : 32B zeros (x-frag quads 2,3 + prefetch guard)
//   fc2 scratch overlays X (16 rows x 144B)
#define LDS_BYTES 18720

typedef _Float16 f16x8 __attribute__((ext_vector_type(8)));
typedef float    f32x4 __attribute__((ext_vector_type(4)));

#define LOG2E     1.44269504088896f
#define TWO_LOG2E 2.88539008177793f

__device__ __forceinline__ float sig_pre(float a) {   // a = -x*log2e
    return __builtin_amdgcn_rcpf(1.0f + __builtin_amdgcn_exp2f(a));
}
__device__ __forceinline__ float tanh_pre(float a) {  // a = 2x*log2e
    return 1.0f - 2.0f * __builtin_amdgcn_rcpf(1.0f + __builtin_amdgcn_exp2f(a));
}
__device__ __forceinline__ int pack2(float a, float b) {  // RTN fp16 pair
    union { _Float16 h[2]; int i; } u;
    u.h[0] = (_Float16)a; u.h[1] = (_Float16)b;
    return u.i;
}

__global__ __launch_bounds__(128, 4)
void lstm_fused(const int* __restrict__ objs,
                const float* __restrict__ boxes,
                const int* __restrict__ preds,
                const int* __restrict__ subj,
                const float* __restrict__ obj_emb,
                const float* __restrict__ pred_emb,
                const float* __restrict__ W_ih,
                const float* __restrict__ W_hh,
                const float* __restrict__ b_ih,
                const float* __restrict__ b_hh,
                const float* __restrict__ fc2_W,
                const float* __restrict__ fc2_b,
                float* __restrict__ out)
{
    extern __shared__ char smem[];
    const int tid  = threadIdx.x;
    const int lane = tid & 63;
    const int wv   = tid >> 6;           // 0 or 1: which gate-half
    const int quad = lane >> 4;          // 0..3
    const int cidx = lane & 15;          // batch index
    const int XOFF = 0, HX0 = 16640, HX1 = 17664, ZOFF = 18688;

    if (tid < 8) ((int*)(smem + ZOFF))[tid] = 0;

    // ---- stage x features (fp16): 128 threads, 4 t each ----
    {
        int b  = tid >> 3;               // 0..15
        int t0 = (tid & 7) << 2;         // 0,4,...,28
        long gb = (long)blockIdx.x * 16 + b;
        int4 ov = *(const int4*)(objs  + gb * 32 + t0);
        int4 pv = *(const int4*)(preds + gb * 32 + t0);
        int4 sv = *(const int4*)(subj  + gb * 32 + t0);
        int oarr[4] = {ov.x, ov.y, ov.z, ov.w};
        int parr[4] = {pv.x, pv.y, pv.z, pv.w};
        int sarr[4] = {sv.x, sv.y, sv.z, sv.w};
        #pragma unroll
        for (int tt = 0; tt < 4; ++tt) {
            int t = t0 + tt;
            const float* eo = obj_emb  + oarr[tt] * 5;
            const float* ep = pred_emb + parr[tt] * 5;
            float4 bx = *(const float4*)(boxes + (gb * 32 + t) * 4);
            f16x8 lo, hi;
            lo[0]=(_Float16)eo[0]; lo[1]=(_Float16)eo[1]; lo[2]=(_Float16)eo[2];
            lo[3]=(_Float16)eo[3]; lo[4]=(_Float16)eo[4];
            lo[5]=(_Float16)ep[0]; lo[6]=(_Float16)ep[1]; lo[7]=(_Float16)ep[2];
            hi[0]=(_Float16)ep[3]; hi[1]=(_Float16)ep[4];
            hi[2]=(_Float16)(sarr[tt]==0 ? 1.0f : 0.0f);
            hi[3]=(_Float16)(sarr[tt]==1 ? 1.0f : 0.0f);
            hi[4]=(_Float16)bx.x; hi[5]=(_Float16)bx.y;
            hi[6]=(_Float16)bx.z; hi[7]=(_Float16)bx.w;
            char* dst = smem + XOFF + b * 1040 + t * 32;
            *(f16x8*)dst        = lo;
            *(f16x8*)(dst + 16) = hi;
        }
    }

    // ---- W fragments: wave wv owns tiles (g, half=wv), g=0..3 (i,f,g,o) ----
    // A-frag row m=cidx -> unit u=8*(m>>2)+(m&3)+4*wv, canonical row n=g*32+u.
    // k = quad*8+jj over K=[x16|pad16|h32].
    f16x8 Wf[4][2];
    f32x4 bias4[4];
    #pragma unroll
    for (int g = 0; g < 4; ++g) {
        float scale = (g == 2) ? TWO_LOG2E : -LOG2E;
        int um = 8 * (cidx >> 2) + (cidx & 3) + 4 * wv;
        int n  = g * 32 + um;
        #pragma unroll
        for (int ks = 0; ks < 2; ++ks) {
            f16x8 v;
            #pragma unroll
            for (int jj = 0; jj < 8; ++jj) {
                int k = ks * 32 + quad * 8 + jj;
                float val = (k < 16) ? W_ih[n * 16 + k]
                          : (k >= 32) ? W_hh[n * 32 + (k - 32)]
                          : 0.0f;
                v[jj] = (_Float16)(val * scale);
            }
            Wf[g][ks] = v;
        }
        #pragma unroll
        for (int r = 0; r < 4; ++r) {
            int ur = 8 * quad + 4 * wv + r;              // D row m=4q+r -> unit
            bias4[g][r] = (b_ih[g * 32 + ur] + b_hh[g * 32 + ur]) * scale;
        }
    }

    // ---- addressing ----
    const bool qlow = (quad < 2);
    int       xaddr = qlow ? (XOFF + cidx * 1040 + quad * 16) : ZOFF;
    const int xinc  = qlow ? 32 : 0;
    const int wr_off = wv * 512 + lane * 8;          // own slot in HX buffer
    const int rd_off = (1 - wv) * 512 + lane * 8;    // partner's slot

    __syncthreads();   // staging visible

    // prime: x[0] MFMAs (bias rides as C); h(0)=0
    f16x8 xfrag = *(const f16x8*)(smem + xaddr); xaddr += xinc;
    f32x4 accp[4];
    #pragma unroll
    for (int g = 0; g < 4; ++g)
        accp[g] = __builtin_amdgcn_mfma_f32_16x16x32_f16(Wf[g][0], xfrag, bias4[g], 0, 0, 0);

    int pk0 = 0, pk1 = 0;        // own packed h (units 8q+4wv+{0..3})
    int rd0 = 0, rd1 = 0;        // partner's packed h
    float cst[4] = {0,0,0,0};
    float hr[4];

    #pragma unroll 2
    for (int t = 0; t < 32; ++t) {
        // B-frag h(t): jj 0..3 = wave0 units, jj 4..7 = wave1 units
        union { int i[4]; f16x8 v; } hf;
        hf.i[0] = wv ? rd0 : pk0;
        hf.i[1] = wv ? rd1 : pk1;
        hf.i[2] = wv ? pk0 : rd0;
        hf.i[3] = wv ? pk1 : rd1;

        f32x4 acc[4];
        #pragma unroll
        for (int g = 0; g < 4; ++g)
            acc[g] = __builtin_amdgcn_mfma_f32_16x16x32_f16(Wf[g][1], hf.v, accp[g], 0, 0, 0);

        // prefetch next x (t=31: reads row-pad / neighbor row — discarded)
        f16x8 xn = *(const f16x8*)(smem + xaddr); xaddr += xinc;

        // activations for this wave's 4 units (batch cidx, unit 8q+4wv+r)
        #pragma unroll
        for (int r = 0; r < 4; ++r) {
            float iv = sig_pre(acc[0][r]);
            float fv = sig_pre(acc[1][r]);
            float gv = tanh_pre(acc[2][r]);
            float ov = sig_pre(acc[3][r]);
            float c  = fmaf(fv, cst[r], iv * gv);
            cst[r] = c;
            hr[r] = ov * tanh_pre(c * TWO_LOG2E);
        }
        pk0 = pack2(hr[0], hr[1]);
        pk1 = pack2(hr[2], hr[3]);

        // publish own half for step t+1 (double-buffered)
        char* buf = smem + ((t & 1) ? HX1 : HX0);
        *(int2*)(buf + wr_off) = (int2){pk0, pk1};

        // x-MFMAs for next step — off the h critical path
        #pragma unroll
        for (int g = 0; g < 4; ++g)
            accp[g] = __builtin_amdgcn_mfma_f32_16x16x32_f16(Wf[g][0], xn, bias4[g], 0, 0, 0);

        __syncthreads();
        int2 rd = *(const int2*)(buf + rd_off);
        rd0 = rd.x; rd1 = rd.y;
    }

    // ---- epilogue: fc2 on final h (fp32 via LDS scratch over X) ----
    __syncthreads();
    #pragma unroll
    for (int r = 0; r < 4; ++r)
        *(float*)(smem + cidx * 144 + (8 * quad + 4 * wv + r) * 4) = hr[r];
    __syncthreads();

    if (tid < 64) {
        int b = tid >> 2, jj = tid & 3;
        const float* fw   = fc2_W + jj * 32;
        const float* hrow = (const float*)(smem + b * 144);
        float s = fc2_b[jj];
        #pragma unroll
        for (int k = 0; k < 8; ++k) {
            float4 hv = *(const float4*)(hrow + k * 4);
            s += fw[k*4+0] * hv.x + fw[k*4+1] * hv.y
               + fw[k*4+2] * hv.z + fw[k*4+3] * hv.w;
        }
        s = fminf(fmaxf(s, 0.0f), 1.0f);
        out[(long)blockIdx.x * 64 + tid] = s;
    }
}

extern "C" void kernel_launch(void* const* d_in, const int* in_sizes, int n_in,
                              void* d_out, int out_size, void* d_ws, size_t ws_size,
                              hipStream_t stream)
{
    // inputs: 0 objs(i32) 1 boxes(f32) 2 preds(i32) 3 subj(i32) 4 target(unused)
    //         5 obj_emb 6 pred_emb 7 W_ih 8 W_hh 9 b_ih 10 b_hh 11 fc2_W 12 fc2_b
    lstm_fused<<<2048, 128, LDS_BYTES, stream>>>(
        (const int*)d_in[0], (const float*)d_in[1], (const int*)d_in[2],
        (const int*)d_in[3],
        (const float*)d_in[5], (const float*)d_in[6],
        (const float*)d_in[7], (const float*)d_in[8],
        (const float*)d_in[9], (const float*)d_in[10],
        (const float*)d_in[11], (const float*)d_in[12],
        (float*)d_out);
}

// Round 6
// 138.293 us; speedup vs baseline: 1.1251x; 1.0383x over previous
//
#include <hip/hip_runtime.h>

// multi_triples_lstm v6: 4-way unit-split, 256-thr WGs -> 8192 waves (8/SIMD,
// 100% occupancy). WG = one 16-batch chain. Wave w owns hidden-unit pairs
// {8q+2w, 8q+2w+1} (q=lane>>4): tile0 = i|f rows of those units, tile1 = g|o
// rows (free row permutation of W). Per wave per step: 2 h-MFMA + 2 x-MFMA +
// 20 trans. Lane's packed h dword IS B-frag dword d=w -> exchange is one
// ds_write_b32 + 4 ds_read_b32 + 1 barrier (double-buffered).
// Scales folded into fp16 weights: i/f/o rows * -log2e, g rows * +2log2e.
//
// LDS (dynamic):
//   X   @ 0     : 16 rows x 1040B (fp16 feats; (b,t) at b*1040 + t*32)
//   HX0 @ 16640 : 1024B (4 waves x 64 lanes x 4B packed h)
//   HX1 @ 17664 : 1024B (double buffer)
//   Z   @ 18688 : 32B zeros (x-frag quads 2,3)
//   fc2 scratch overlays X (16 rows x 144B)
#define LDS_BYTES 18720

typedef _Float16 f16x8 __attribute__((ext_vector_type(8)));
typedef float    f32x4 __attribute__((ext_vector_type(4)));

#define LOG2E     1.44269504088896f
#define TWO_LOG2E 2.88539008177793f

__device__ __forceinline__ float sig_pre(float a) {   // a = -x*log2e
    return __builtin_amdgcn_rcpf(1.0f + __builtin_amdgcn_exp2f(a));
}
__device__ __forceinline__ float tanh_pre(float a) {  // a = 2x*log2e
    return 1.0f - 2.0f * __builtin_amdgcn_rcpf(1.0f + __builtin_amdgcn_exp2f(a));
}
__device__ __forceinline__ int pack2(float a, float b) {  // RTN fp16 pair
    union { _Float16 h[2]; int i; } u;
    u.h[0] = (_Float16)a; u.h[1] = (_Float16)b;
    return u.i;
}

__global__ __launch_bounds__(256, 8)
void lstm_fused(const int* __restrict__ objs,
                const float* __restrict__ boxes,
                const int* __restrict__ preds,
                const int* __restrict__ subj,
                const float* __restrict__ obj_emb,
                const float* __restrict__ pred_emb,
                const float* __restrict__ W_ih,
                const float* __restrict__ W_hh,
                const float* __restrict__ b_ih,
                const float* __restrict__ b_hh,
                const float* __restrict__ fc2_W,
                const float* __restrict__ fc2_b,
                float* __restrict__ out)
{
    extern __shared__ char smem[];
    const int tid  = threadIdx.x;
    const int lane = tid & 63;
    const int wv   = tid >> 6;           // 0..3: which unit-pair quarter
    const int quad = lane >> 4;          // 0..3
    const int cidx = lane & 15;          // batch index
    const int XOFF = 0, HX0 = 16640, HX1 = 17664, ZOFF = 18688;

    if (tid < 8) ((int*)(smem + ZOFF))[tid] = 0;

    // ---- stage x features (fp16): 256 threads, 2 t each ----
    {
        int b  = tid >> 4;               // 0..15
        int t0 = (tid & 15) << 1;        // 0,2,...,30
        long gb = (long)blockIdx.x * 16 + b;
        int2 ov = *(const int2*)(objs  + gb * 32 + t0);
        int2 pv = *(const int2*)(preds + gb * 32 + t0);
        int2 sv = *(const int2*)(subj  + gb * 32 + t0);
        int oarr[2] = {ov.x, ov.y};
        int parr[2] = {pv.x, pv.y};
        int sarr[2] = {sv.x, sv.y};
        #pragma unroll
        for (int tt = 0; tt < 2; ++tt) {
            int t = t0 + tt;
            const float* eo = obj_emb  + oarr[tt] * 5;
            const float* ep = pred_emb + parr[tt] * 5;
            float4 bx = *(const float4*)(boxes + (gb * 32 + t) * 4);
            f16x8 lo, hi;
            lo[0]=(_Float16)eo[0]; lo[1]=(_Float16)eo[1]; lo[2]=(_Float16)eo[2];
            lo[3]=(_Float16)eo[3]; lo[4]=(_Float16)eo[4];
            lo[5]=(_Float16)ep[0]; lo[6]=(_Float16)ep[1]; lo[7]=(_Float16)ep[2];
            hi[0]=(_Float16)ep[3]; hi[1]=(_Float16)ep[4];
            hi[2]=(_Float16)(sarr[tt]==0 ? 1.0f : 0.0f);
            hi[3]=(_Float16)(sarr[tt]==1 ? 1.0f : 0.0f);
            hi[4]=(_Float16)bx.x; hi[5]=(_Float16)bx.y;
            hi[6]=(_Float16)bx.z; hi[7]=(_Float16)bx.w;
            char* dst = smem + XOFF + b * 1040 + t * 32;
            *(f16x8*)dst        = lo;
            *(f16x8*)(dst + 16) = hi;
        }
    }

    // ---- W fragments: wave wv, tile row m: unit u=8*(m>>2)+2*wv+(m&1),
    //      gate = tile*2 + ((m&3)>>1)  (0=i,1=f,2=g,3=o; canonical n=g*32+u)
    f16x8 Wf[2][2];
    f32x4 bias4[2];
    #pragma unroll
    for (int tile = 0; tile < 2; ++tile) {
        int rm   = cidx & 3;
        int u    = 8 * (cidx >> 2) + 2 * wv + (rm & 1);
        int gate = tile * 2 + (rm >> 1);
        float scale = (gate == 2) ? TWO_LOG2E : -LOG2E;
        int n = gate * 32 + u;
        #pragma unroll
        for (int ks = 0; ks < 2; ++ks) {
            f16x8 v;
            #pragma unroll
            for (int jj = 0; jj < 8; ++jj) {
                int k = ks * 32 + quad * 8 + jj;
                float val = (k < 16) ? W_ih[n * 16 + k]
                          : (k >= 32) ? W_hh[n * 32 + (k - 32)]
                          : 0.0f;
                v[jj] = (_Float16)(val * scale);
            }
            Wf[tile][ks] = v;
        }
        #pragma unroll
        for (int r = 0; r < 4; ++r) {
            int ur = 8 * quad + 2 * wv + (r & 1);
            int gr = tile * 2 + (r >> 1);
            float sc = (gr == 2) ? TWO_LOG2E : -LOG2E;
            bias4[tile][r] = (b_ih[gr * 32 + ur] + b_hh[gr * 32 + ur]) * sc;
        }
    }

    // ---- addressing ----
    const bool qlow = (quad < 2);
    int       xaddr = qlow ? (XOFF + cidx * 1040 + quad * 16) : ZOFF;
    const int xinc  = qlow ? 32 : 0;
    const int slot  = lane * 4;                      // dword slot in HX buffer

    __syncthreads();   // staging visible

    // prime: x[0] MFMAs (bias rides as C); h(0)=0
    f16x8 xfrag = *(const f16x8*)(smem + xaddr); xaddr += xinc;
    f32x4 accp[2];
    #pragma unroll
    for (int tile = 0; tile < 2; ++tile)
        accp[tile] = __builtin_amdgcn_mfma_f32_16x16x32_f16(Wf[tile][0], xfrag, bias4[tile], 0, 0, 0);

    union { int i[4]; f16x8 v; } hf;
    hf.i[0] = 0; hf.i[1] = 0; hf.i[2] = 0; hf.i[3] = 0;
    float cst[2] = {0, 0};
    float h0, h1;

    #pragma unroll 2
    for (int t = 0; t < 32; ++t) {
        // h-MFMAs: acc0 = {i(u0),i(u1),f(u0),f(u1)}, acc1 = {g,g,o,o}
        f32x4 acc0 = __builtin_amdgcn_mfma_f32_16x16x32_f16(Wf[0][1], hf.v, accp[0], 0, 0, 0);
        f32x4 acc1 = __builtin_amdgcn_mfma_f32_16x16x32_f16(Wf[1][1], hf.v, accp[1], 0, 0, 0);

        // prefetch next x (t=31 reads row pad — discarded)
        f16x8 xn = *(const f16x8*)(smem + xaddr); xaddr += xinc;

        float i0 = sig_pre(acc0[0]);
        float i1 = sig_pre(acc0[1]);
        float f0 = sig_pre(acc0[2]);
        float f1 = sig_pre(acc0[3]);
        float g0 = tanh_pre(acc1[0]);
        float g1 = tanh_pre(acc1[1]);
        float o0 = sig_pre(acc1[2]);
        float o1 = sig_pre(acc1[3]);
        float c0 = fmaf(f0, cst[0], i0 * g0);
        float c1 = fmaf(f1, cst[1], i1 * g1);
        cst[0] = c0; cst[1] = c1;
        h0 = o0 * tanh_pre(c0 * TWO_LOG2E);
        h1 = o1 * tanh_pre(c1 * TWO_LOG2E);
        int pk = pack2(h0, h1);

        // publish own dword (= B-frag dword wv), double-buffered
        char* buf = smem + ((t & 1) ? HX1 : HX0);
        *(int*)(buf + wv * 256 + slot) = pk;

        // x-MFMAs for next step — off the h critical path
        accp[0] = __builtin_amdgcn_mfma_f32_16x16x32_f16(Wf[0][0], xn, bias4[0], 0, 0, 0);
        accp[1] = __builtin_amdgcn_mfma_f32_16x16x32_f16(Wf[1][0], xn, bias4[1], 0, 0, 0);

        __syncthreads();
        // gather full h: dword d = units 8q+2d,8q+2d+1 (own slot d=wv = pk)
        hf.i[0] = *(const int*)(buf + 0   + slot);
        hf.i[1] = *(const int*)(buf + 256 + slot);
        hf.i[2] = *(const int*)(buf + 512 + slot);
        hf.i[3] = *(const int*)(buf + 768 + slot);
    }

    // ---- epilogue: fc2 on final h (fp32 via LDS scratch over X) ----
    __syncthreads();
    {
        int u0 = 8 * quad + 2 * wv;
        *(float2*)(smem + cidx * 144 + u0 * 4) = (float2){h0, h1};
    }
    __syncthreads();

    if (tid < 64) {
        int b = tid >> 2, jj = tid & 3;
        const float* fw   = fc2_W + jj * 32;
        const float* hrow = (const float*)(smem + b * 144);
        float s = fc2_b[jj];
        #pragma unroll
        for (int k = 0; k < 8; ++k) {
            float4 hv = *(const float4*)(hrow + k * 4);
            s += fw[k*4+0] * hv.x + fw[k*4+1] * hv.y
               + fw[k*4+2] * hv.z + fw[k*4+3] * hv.w;
        }
        s = fminf(fmaxf(s, 0.0f), 1.0f);
        out[(long)blockIdx.x * 64 + tid] = s;
    }
}

extern "C" void kernel_launch(void* const* d_in, const int* in_sizes, int n_in,
                              void* d_out, int out_size, void* d_ws, size_t ws_size,
                              hipStream_t stream)
{
    // inputs: 0 objs(i32) 1 boxes(f32) 2 preds(i32) 3 subj(i32) 4 target(unused)
    //         5 obj_emb 6 pred_emb 7 W_ih 8 W_hh 9 b_ih 10 b_hh 11 fc2_W 12 fc2_b
    lstm_fused<<<2048, 256, LDS_BYTES, stream>>>(
        (const int*)d_in[0], (const float*)d_in[1], (const int*)d_in[2],
        (const int*)d_in[3],
        (const float*)d_in[5], (const float*)d_in[6],
        (const float*)d_in[7], (const float*)d_in[8],
        (const float*)d_in[9], (const float*)d_in[10],
        (const float*)d_in[11], (const float*)d_in[12],
        (float*)d_out);
}

// Round 7
// 133.659 us; speedup vs baseline: 1.1641x; 1.0347x over previous
//
#include <hip/hip_runtime.h>

// multi_triples_lstm v7: v6 skeleton (4-way unit-split, 256-thr WGs, 2048 WGs)
// + shared-denominator activation algebra (7 trans/unit-step instead of 10):
//     Ei=e^{-ai}, Ef=e^{-af}, Eg=e^{2ag}, Eo=e^{-ao}, Ec=e^{2c}
//     c = [cp*(1+Ei)(1+Eg) + (Eg-1)(1+Ef)] * rcp((1+Ef)(1+Ei)(1+Eg))
//     h = (Ec-1) * rcp((1+Eo)(1+Ec))
// + per-WG s_sleep stagger to de-phase the 8 WGs/CU (trans-burst collisions).
// Scales folded into fp16 weights: i/f/o rows * -log2e, g rows * +2log2e.
//
// LDS (dynamic):
//   X   @ 0     : 16 rows x 1040B (fp16 feats; (b,t) at b*1040 + t*32)
//   HX0 @ 16640 : 1024B (4 waves x 64 lanes x 4B packed h)
//   HX1 @ 17664 : 1024B (double buffer)
//   Z   @ 18688 : 32B zeros (x-frag quads 2,3)
//   fc2 scratch overlays X (16 rows x 144B)
#define LDS_BYTES 18720

typedef _Float16 f16x8 __attribute__((ext_vector_type(8)));
typedef float    f32x4 __attribute__((ext_vector_type(4)));

#define LOG2E     1.44269504088896f
#define TWO_LOG2E 2.88539008177793f

__device__ __forceinline__ int pack2(float a, float b) {  // RTN fp16 pair
    union { _Float16 h[2]; int i; } u;
    u.h[0] = (_Float16)a; u.h[1] = (_Float16)b;
    return u.i;
}

__global__ __launch_bounds__(256, 8)
void lstm_fused(const int* __restrict__ objs,
                const float* __restrict__ boxes,
                const int* __restrict__ preds,
                const int* __restrict__ subj,
                const float* __restrict__ obj_emb,
                const float* __restrict__ pred_emb,
                const float* __restrict__ W_ih,
                const float* __restrict__ W_hh,
                const float* __restrict__ b_ih,
                const float* __restrict__ b_hh,
                const float* __restrict__ fc2_W,
                const float* __restrict__ fc2_b,
                float* __restrict__ out)
{
    extern __shared__ char smem[];
    const int tid  = threadIdx.x;
    const int lane = tid & 63;
    const int wv   = tid >> 6;           // 0..3: which unit-pair quarter
    const int quad = lane >> 4;          // 0..3
    const int cidx = lane & 15;          // batch index
    const int XOFF = 0, HX0 = 16640, HX1 = 17664, ZOFF = 18688;

    if (tid < 8) ((int*)(smem + ZOFF))[tid] = 0;

    // ---- stage x features (fp16): 256 threads, 2 t each ----
    {
        int b  = tid >> 4;               // 0..15
        int t0 = (tid & 15) << 1;        // 0,2,...,30
        long gb = (long)blockIdx.x * 16 + b;
        int2 ov = *(const int2*)(objs  + gb * 32 + t0);
        int2 pv = *(const int2*)(preds + gb * 32 + t0);
        int2 sv = *(const int2*)(subj  + gb * 32 + t0);
        int oarr[2] = {ov.x, ov.y};
        int parr[2] = {pv.x, pv.y};
        int sarr[2] = {sv.x, sv.y};
        #pragma unroll
        for (int tt = 0; tt < 2; ++tt) {
            int t = t0 + tt;
            const float* eo = obj_emb  + oarr[tt] * 5;
            const float* ep = pred_emb + parr[tt] * 5;
            float4 bx = *(const float4*)(boxes + (gb * 32 + t) * 4);
            f16x8 lo, hi;
            lo[0]=(_Float16)eo[0]; lo[1]=(_Float16)eo[1]; lo[2]=(_Float16)eo[2];
            lo[3]=(_Float16)eo[3]; lo[4]=(_Float16)eo[4];
            lo[5]=(_Float16)ep[0]; lo[6]=(_Float16)ep[1]; lo[7]=(_Float16)ep[2];
            hi[0]=(_Float16)ep[3]; hi[1]=(_Float16)ep[4];
            hi[2]=(_Float16)(sarr[tt]==0 ? 1.0f : 0.0f);
            hi[3]=(_Float16)(sarr[tt]==1 ? 1.0f : 0.0f);
            hi[4]=(_Float16)bx.x; hi[5]=(_Float16)bx.y;
            hi[6]=(_Float16)bx.z; hi[7]=(_Float16)bx.w;
            char* dst = smem + XOFF + b * 1040 + t * 32;
            *(f16x8*)dst        = lo;
            *(f16x8*)(dst + 16) = hi;
        }
    }

    // ---- W fragments: wave wv, tile row m: unit u=8*(m>>2)+2*wv+(m&1),
    //      gate = tile*2 + ((m&3)>>1)  (0=i,1=f,2=g,3=o; canonical n=g*32+u)
    f16x8 Wf[2][2];
    f32x4 bias4[2];
    #pragma unroll
    for (int tile = 0; tile < 2; ++tile) {
        int rm   = cidx & 3;
        int u    = 8 * (cidx >> 2) + 2 * wv + (rm & 1);
        int gate = tile * 2 + (rm >> 1);
        float scale = (gate == 2) ? TWO_LOG2E : -LOG2E;
        int n = gate * 32 + u;
        #pragma unroll
        for (int ks = 0; ks < 2; ++ks) {
            f16x8 v;
            #pragma unroll
            for (int jj = 0; jj < 8; ++jj) {
                int k = ks * 32 + quad * 8 + jj;
                float val = (k < 16) ? W_ih[n * 16 + k]
                          : (k >= 32) ? W_hh[n * 32 + (k - 32)]
                          : 0.0f;
                v[jj] = (_Float16)(val * scale);
            }
            Wf[tile][ks] = v;
        }
        #pragma unroll
        for (int r = 0; r < 4; ++r) {
            int ur = 8 * quad + 2 * wv + (r & 1);
            int gr = tile * 2 + (r >> 1);
            float sc = (gr == 2) ? TWO_LOG2E : -LOG2E;
            bias4[tile][r] = (b_ih[gr * 32 + ur] + b_hh[gr * 32 + ur]) * sc;
        }
    }

    // ---- addressing ----
    const bool qlow = (quad < 2);
    int       xaddr = qlow ? (XOFF + cidx * 1040 + quad * 16) : ZOFF;
    const int xinc  = qlow ? 32 : 0;
    const int slot  = lane * 4;                      // dword slot in HX buffer

    // de-phase the 8 WGs sharing a CU (~0..4k cyc pseudo-random stagger)
    {
        int del = (blockIdx.x * 37) & 31;
        while (del--) asm volatile("s_sleep 2" ::: "memory");
    }

    __syncthreads();   // staging visible

    // prime: x[0] MFMAs (bias rides as C); h(0)=0
    f16x8 xfrag = *(const f16x8*)(smem + xaddr); xaddr += xinc;
    f32x4 accp[2];
    #pragma unroll
    for (int tile = 0; tile < 2; ++tile)
        accp[tile] = __builtin_amdgcn_mfma_f32_16x16x32_f16(Wf[tile][0], xfrag, bias4[tile], 0, 0, 0);

    union { int i[4]; f16x8 v; } hf;
    hf.i[0] = 0; hf.i[1] = 0; hf.i[2] = 0; hf.i[3] = 0;
    float cst[2] = {0, 0};
    float h0, h1;

    #pragma unroll 2
    for (int t = 0; t < 32; ++t) {
        // h-MFMAs: acc0 = {i(u0),i(u1),f(u0),f(u1)}, acc1 = {g(u0),g(u1),o(u0),o(u1)}
        f32x4 acc0 = __builtin_amdgcn_mfma_f32_16x16x32_f16(Wf[0][1], hf.v, accp[0], 0, 0, 0);
        f32x4 acc1 = __builtin_amdgcn_mfma_f32_16x16x32_f16(Wf[1][1], hf.v, accp[1], 0, 0, 0);

        // prefetch next x (t=31 reads row pad — discarded)
        f16x8 xn = *(const f16x8*)(smem + xaddr); xaddr += xinc;

        // shared-denominator activations (7 trans per unit)
        float Ei0 = __builtin_amdgcn_exp2f(acc0[0]);
        float Ei1 = __builtin_amdgcn_exp2f(acc0[1]);
        float Ef0 = __builtin_amdgcn_exp2f(acc0[2]);
        float Ef1 = __builtin_amdgcn_exp2f(acc0[3]);
        float Eg0 = __builtin_amdgcn_exp2f(acc1[0]);
        float Eg1 = __builtin_amdgcn_exp2f(acc1[1]);
        float Eo0 = __builtin_amdgcn_exp2f(acc1[2]);
        float Eo1 = __builtin_amdgcn_exp2f(acc1[3]);

        float t10  = 1.0f + Ei0;
        float t11  = 1.0f + Ei1;
        float dig0 = fmaf(t10, Eg0, t10);            // (1+Ei)(1+Eg)
        float dig1 = fmaf(t11, Eg1, t11);
        float tf0  = 1.0f + Ef0;
        float tf1  = 1.0f + Ef1;
        float n0   = fmaf(Eg0 - 1.0f, tf0, cst[0] * dig0);
        float n1   = fmaf(Eg1 - 1.0f, tf1, cst[1] * dig1);
        float c0   = n0 * __builtin_amdgcn_rcpf(tf0 * dig0);
        float c1   = n1 * __builtin_amdgcn_rcpf(tf1 * dig1);
        cst[0] = c0; cst[1] = c1;
        float Ec0  = __builtin_amdgcn_exp2f(c0 * TWO_LOG2E);
        float Ec1  = __builtin_amdgcn_exp2f(c1 * TWO_LOG2E);
        float to0  = 1.0f + Eo0;
        float to1  = 1.0f + Eo1;
        float dh0  = fmaf(to0, Ec0, to0);            // (1+Eo)(1+Ec)
        float dh1  = fmaf(to1, Ec1, to1);
        h0 = (Ec0 - 1.0f) * __builtin_amdgcn_rcpf(dh0);
        h1 = (Ec1 - 1.0f) * __builtin_amdgcn_rcpf(dh1);
        int pk = pack2(h0, h1);

        // publish own dword (= B-frag dword wv), double-buffered
        char* buf = smem + ((t & 1) ? HX1 : HX0);
        *(int*)(buf + wv * 256 + slot) = pk;

        // x-MFMAs for next step — off the h critical path
        accp[0] = __builtin_amdgcn_mfma_f32_16x16x32_f16(Wf[0][0], xn, bias4[0], 0, 0, 0);
        accp[1] = __builtin_amdgcn_mfma_f32_16x16x32_f16(Wf[1][0], xn, bias4[1], 0, 0, 0);

        __syncthreads();
        // gather full h: dword d = units 8q+2d,8q+2d+1 (own slot d=wv = pk)
        hf.i[0] = *(const int*)(buf + 0   + slot);
        hf.i[1] = *(const int*)(buf + 256 + slot);
        hf.i[2] = *(const int*)(buf + 512 + slot);
        hf.i[3] = *(const int*)(buf + 768 + slot);
    }

    // ---- epilogue: fc2 on final h (fp32 via LDS scratch over X) ----
    __syncthreads();
    {
        int u0 = 8 * quad + 2 * wv;
        *(float2*)(smem + cidx * 144 + u0 * 4) = (float2){h0, h1};
    }
    __syncthreads();

    if (tid < 64) {
        int b = tid >> 2, jj = tid & 3;
        const float* fw   = fc2_W + jj * 32;
        const float* hrow = (const float*)(smem + b * 144);
        float s = fc2_b[jj];
        #pragma unroll
        for (int k = 0; k < 8; ++k) {
            float4 hv = *(const float4*)(hrow + k * 4);
            s += fw[k*4+0] * hv.x + fw[k*4+1] * hv.y
               + fw[k*4+2] * hv.z + fw[k*4+3] * hv.w;
        }
        s = fminf(fmaxf(s, 0.0f), 1.0f);
        out[(long)blockIdx.x * 64 + tid] = s;
    }
}

extern "C" void kernel_launch(void* const* d_in, const int* in_sizes, int n_in,
                              void* d_out, int out_size, void* d_ws, size_t ws_size,
                              hipStream_t stream)
{
    // inputs: 0 objs(i32) 1 boxes(f32) 2 preds(i32) 3 subj(i32) 4 target(unused)
    //         5 obj_emb 6 pred_emb 7 W_ih 8 W_hh 9 b_ih 10 b_hh 11 fc2_W 12 fc2_b
    lstm_fused<<<2048, 256, LDS_BYTES, stream>>>(
        (const int*)d_in[0], (const float*)d_in[1], (const int*)d_in[2],
        (const int*)d_in[3],
        (const float*)d_in[5], (const float*)d_in[6],
        (const float*)d_in[7], (const float*)d_in[8],
        (const float*)d_in[9], (const float*)d_in[10],
        (const float*)d_in[11], (const float*)d_in[12],
        (float*)d_out);
}